// Round 3
// baseline (546.178 us; speedup 1.0000x reference)
//
#include <hip/hip_runtime.h>
#include <hip/hip_bf16.h>

// MHA forward. B=4, T=2048, D=1024, H=16, Hd=64. Inputs auto-detected f32/bf16.
// convert x -> fused convert+transpose weights -> QKV GEMM(+bias; Q pre-scaled by
// log2e/8; V written transposed to vT in-epilogue) -> flash attention v11
// (NO LDS, NO barriers: K/V read direct from global via L1/L2; XCD-chunked
// block swizzle keeps per-XCD K/V working set ~4MB=L2) -> out GEMM(+bias).
// R4: never cap occupancy via __launch_bounds__ 2nd arg (spill disaster).
// R5: don't interleave P LDS writes into PV chain. R6: keep S live range to one kb.
// R7: all single-buffer variants stall ~120us on per-tile barrier drain.
// R8: v8 latency-bound at 2 waves/SIMD; v9 512-thr 32q/wave -> 4 waves/SIMD (101us).
// R9: v10 manual pipeline+stagger+setprio REGRESSED (127us, Mfma 43->34): manual
//     ordering defeats compiler sched (m141); barrier re-syncs waves so stagger
//     can't create overlap. Reverted.
// R10 (this round): v9's barrier-locked LDS tile loop is the non-overlap cause;
//     K/V per head = 512KB = L2-resident (m169: LDS-staging L2-fit data is pure
//     overhead). v11 reads K/V direct from global: no barriers (waves free-run,
//     pipes overlap naturally), no LDS reads/conflicts, less addr VALU.

typedef __bf16 bf16_t;
typedef __bf16 bf16x8 __attribute__((ext_vector_type(8)));
typedef float f32x4 __attribute__((ext_vector_type(4)));
typedef short short4v __attribute__((ext_vector_type(4)));

#if __has_builtin(__builtin_amdgcn_mfma_f32_16x16x16_bf16)
typedef __bf16 bf16x4 __attribute__((ext_vector_type(4)));
#define MFMA_PV(va, vb, c) __builtin_amdgcn_mfma_f32_16x16x16_bf16( \
    __builtin_bit_cast(bf16x4, (va)), __builtin_bit_cast(bf16x4, (vb)), (c), 0, 0, 0)
#else
#define MFMA_PV(va, vb, c) __builtin_amdgcn_mfma_f32_16x16x16bf16_1k((va), (vb), (c), 0, 0, 0)
#endif

#define DMODEL 1024
#define NH     16
#define HD     64
#define BATCH  4
#define SEQ    2048
#define NTOK   (BATCH * SEQ)      // 8192
#define NOUT   (NTOK * DMODEL)    // 8388608
#define CEXP   0.1803368801111204f   // log2(e)/sqrt(64)

__device__ __forceinline__ void async_ld16(void* lds, const void* g) {
  __builtin_amdgcn_global_load_lds(
      (const __attribute__((address_space(1))) void*)g,
      (__attribute__((address_space(3))) void*)lds, 16, 0, 0);
}

// ------------------------------------------------------------- dtype sniff
// 8192 u16 samples via vectorized loads; f32 data -> ~32 NaN-pattern low halves.
__global__ __launch_bounds__(256) void sniff_dtype(
    const uint4* __restrict__ x, int* __restrict__ flag) {
  int t = threadIdx.x;
  uint4 v = x[t];   // 8 u16 per thread x 256 = 2048... use 4 loads
  int nanish = 0, zc = 0;
  for (int j = 0; j < 4; ++j) {
    uint4 w = x[t + j * 256];
    unsigned u[4] = {w.x, w.y, w.z, w.w};
    for (int k = 0; k < 4; ++k) {
      unsigned lo = u[k] & 0xFFFFu, hi = u[k] >> 16;
      if ((lo & 0x7F80u) == 0x7F80u) nanish++;
      if ((hi & 0x7F80u) == 0x7F80u) nanish++;
      if (lo == 0) zc++;
      if (hi == 0) zc++;
    }
  }
  (void)v;
  __shared__ int rn[256], rz[256];
  rn[t] = nanish; rz[t] = zc;
  __syncthreads();
  for (int s = 128; s > 0; s >>= 1) {
    if (t < s) { rn[t] += rn[t + s]; rz[t] += rz[t + s]; }
    __syncthreads();
  }
  if (t == 0) flag[0] = (rn[0] > 4 || rz[0] > 2048) ? 1 : 0;  // 1 = f32 inputs
}

// ------------------------------------------------------------- converters
__global__ __launch_bounds__(256) void conv_to_bf16(
    const void* __restrict__ src, bf16_t* __restrict__ dst, int n,
    const int* __restrict__ flag) {
  int i = (blockIdx.x * 256 + threadIdx.x) * 8;
  if (i >= n) return;
  if (flag[0]) {
    const float4* s = (const float4*)((const float*)src + i);
    float4 a = s[0], b = s[1];
    bf16_t* o = dst + i;
    o[0] = (bf16_t)a.x; o[1] = (bf16_t)a.y; o[2] = (bf16_t)a.z; o[3] = (bf16_t)a.w;
    o[4] = (bf16_t)b.x; o[5] = (bf16_t)b.y; o[6] = (bf16_t)b.z; o[7] = (bf16_t)b.w;
  } else {
    *(uint4*)(dst + i) = *(const uint4*)((const bf16_t*)src + i);
  }
}

__global__ __launch_bounds__(256) void conv_biases(
    const void* __restrict__ sq, const void* __restrict__ so,
    float* __restrict__ dq, float* __restrict__ dofs,
    const int* __restrict__ flag) {
  int i = blockIdx.x * 256 + threadIdx.x;
  if (i < 3072)
    dq[i] = flag[0] ? ((const float*)sq)[i] : (float)((const bf16_t*)sq)[i];
  else {
    int j = i - 3072;
    dofs[j] = flag[0] ? ((const float*)so)[j] : (float)((const bf16_t*)so)[j];
  }
}

// ------------------------------------------------------------- weight transpose
__global__ __launch_bounds__(256) void transpose_w(
    const void* __restrict__ in, bf16_t* __restrict__ out, int R, int C,
    const int* __restrict__ flag) {
  __shared__ bf16_t tile[32][33];
  const int tx = threadIdx.x & 31, ty = threadIdx.x >> 5;
  const int c0 = blockIdx.x * 32, r0 = blockIdx.y * 32;
  if (flag[0]) {
    for (int i = 0; i < 4; ++i) {
      int r = ty + i * 8;
      tile[r][tx] = (bf16_t)((const float*)in)[(size_t)(r0 + r) * C + c0 + tx];
    }
  } else {
    for (int i = 0; i < 4; ++i) {
      int r = ty + i * 8;
      tile[r][tx] = ((const bf16_t*)in)[(size_t)(r0 + r) * C + c0 + tx];
    }
  }
  __syncthreads();
  for (int i = 0; i < 4; ++i) {
    int r = ty + i * 8;
    out[(size_t)(c0 + r) * R + r0 + tx] = tile[tx][r];
  }
}

// ------------------------------------------------------------- GEMM (B^T) + f32 bias
// MODE 1: dyn f32/bf16 per flag. MODE 2: QKV epilogue — Q cols (<1024) scaled by
// CEXP; V cols (>=2048) written transposed into vT[b][h][d][seq]; K cols plain.
// Grid is XCD-swizzled (bijective m204 form; both grids are %8==0).
template <int MODE>
__global__ __launch_bounds__(256) void gemm_bt_bias(
    const bf16_t* __restrict__ A, const bf16_t* __restrict__ Bt,
    const float* __restrict__ bias, void* __restrict__ Cout,
    int M, int N, int K, const int* __restrict__ flag,
    bf16_t* __restrict__ vT) {
  __shared__ bf16_t sA[128 * 32];
  __shared__ bf16_t sB[128 * 32];
  const int t = threadIdx.x;
  const int wave = t >> 6, lane = t & 63;
  const int quad = lane >> 4, l16 = lane & 15;
  // XCD-aware bijective remap: consecutive new ids stay on one XCD's L2.
  const int nwg = gridDim.x * gridDim.y;
  const int lin = blockIdx.y * gridDim.x + blockIdx.x;
  const int cpx = nwg >> 3;                    // nwg % 8 == 0 for our grids
  const int swz = (lin & 7) * cpx + (lin >> 3);
  const int bx = swz % gridDim.x, by = swz / gridDim.x;
  const int bM = by * 128, bN = bx * 128;
  const int m0w = (wave >> 1) * 64, n0w = (wave & 1) * 64;
  const int rowS = wave * 16 + (lane >> 2);
  const int kcS = (lane & 3) * 8;

  f32x4 acc[4][4] = {};

  for (int k0 = 0; k0 < K; k0 += 32) {
    for (int r = 0; r < 2; ++r) {
      int row = r * 64 + rowS;
      async_ld16((char*)sA + r * 4096 + wave * 1024,
                 A + (size_t)(bM + row) * K + k0 + kcS);
      async_ld16((char*)sB + r * 4096 + wave * 1024,
                 Bt + (size_t)(bN + row) * K + k0 + kcS);
    }
    __syncthreads();

    bf16x8 af[4], bfr[4];
    for (int i = 0; i < 4; ++i)
      af[i] = *(const bf16x8*)&sA[(m0w + i * 16 + l16) * 32 + quad * 8];
    for (int j = 0; j < 4; ++j)
      bfr[j] = *(const bf16x8*)&sB[(n0w + j * 16 + l16) * 32 + quad * 8];
    for (int i = 0; i < 4; ++i)
      for (int j = 0; j < 4; ++j)
        acc[i][j] = __builtin_amdgcn_mfma_f32_16x16x32_bf16(af[i], bfr[j], acc[i][j], 0, 0, 0);
    __syncthreads();
  }

  const bool f32out = (MODE == 1) && flag[0];
  for (int j = 0; j < 4; ++j) {
    int col = bN + n0w + j * 16 + l16;
    float bv = bias[col];
    for (int i = 0; i < 4; ++i) {
      int row0 = bM + m0w + i * 16 + quad * 4;
      if (MODE == 2 && col >= 2048) {
        // V column -> vT[b][h][d][s], 4 consecutive tokens packed (8B store)
        int hh = (col - 2048) >> 6, dd = (col - 2048) & 63;
        bf16_t o4[4];
        for (int r = 0; r < 4; ++r) o4[r] = (bf16_t)(acc[i][j][r] + bv);
        size_t dst = ((((size_t)(row0 >> 11) * NH + hh) * HD + dd) << 11) | (row0 & 2047);
        *(uint2*)&vT[dst] = *(uint2*)o4;
      } else {
        float scale = (MODE == 2 && col < 1024) ? CEXP : 1.0f;
        for (int r = 0; r < 4; ++r) {
          float v = (acc[i][j][r] + bv) * scale;
          if (f32out) ((float*)Cout)[(size_t)(row0 + r) * N + col] = v;
          else        ((bf16_t*)Cout)[(size_t)(row0 + r) * N + col] = (bf16_t)v;
        }
      }
    }
  }
}

// ------------------------------------------------------------- flash attention v11
// Grid 512 blocks x 512 thr. NO LDS, NO barriers: K/V read direct from global.
// Per head K+V = 512KB (L2-resident); XCD-chunked swizzle assigns 8 heads x all
// 8 q-chunks per XCD -> 4MB working set = one XCD L2. Each wave owns 32 q
// (2 subtiles) x all 64 d. Per 16-key step: K-frag 2x16B loads (full 128B row
// consumed -> L1 reuse x16 waves), V-frag 4x8B loads (32B/row/step, streams
// along vT rows). S^T via 16x16x32 (Q pre-scaled by CEXP in gemm1); exp2
// direct; PV via 16x16x16 (B operand == S^T C-layout) from regs. Waves
// free-run -> MFMA/VALU bursts of different waves overlap naturally.
__global__ __launch_bounds__(512) void attention_v11(
    const bf16_t* __restrict__ qkv, const bf16_t* __restrict__ vT,
    bf16_t* __restrict__ attn) {
  const int t = threadIdx.x;
  const int wave = t >> 6, lane = t & 63;           // wave 0..7
  const int quad = lane >> 4, l16 = lane & 15;
  // XCD-chunked block swizzle (perf-only bijection on 512 blocks).
  const int lin = blockIdx.y * gridDim.x + blockIdx.x;   // 0..511
  const int xcd = lin & 7, j = lin >> 3;                 // j: 0..63
  const int bh = xcd * 8 + (j & 7);
  const int qy = j >> 3;                                 // 0..7
  const int b = bh >> 4, h = bh & 15;
  const int qw = qy * 256 + wave * 32;

  const bf16_t* qglob = qkv + (size_t)b * SEQ * 3072 + h * 64;
  const bf16_t* kglob = qglob + 1024;
  const bf16_t* vglob = vT + (size_t)bh * HD * SEQ;

  bf16x8 qf[2][2];
  for (int s = 0; s < 2; ++s) {
    const bf16_t* qrow = qglob + (size_t)(qw + s * 16 + l16) * 3072 + quad * 8;
    qf[s][0] = *(const bf16x8*)qrow;
    qf[s][1] = *(const bf16x8*)(qrow + 32);
  }

  f32x4 accO[2][4] = {};
  f32x4 lp[2] = {};               // 4 independent partial-sum chains per subtile

  // K: lane reads key = kk + l16, d = quad*8..+7 (kf0) and +32 (kf1).
  const bf16_t* krow = kglob + (size_t)l16 * 3072 + quad * 8;
  // V: lane reads d = db*16 + l16, keys = kk + quad*4..+3 (8B).
  const bf16_t* vrow = vglob + (size_t)l16 * SEQ + quad * 4;

#pragma unroll 2
  for (int kk = 0; kk < SEQ; kk += 16) {
    bf16x8 kf0 = *(const bf16x8*)(krow);
    bf16x8 kf1 = *(const bf16x8*)(krow + 32);
    short4v vf[4];
    for (int db = 0; db < 4; ++db)
      vf[db] = *(const short4v*)(vrow + (size_t)db * 16 * SEQ);

    short4v pB[2];
    for (int s = 0; s < 2; ++s) {
      f32x4 z = {0.f, 0.f, 0.f, 0.f};
      f32x4 st = __builtin_amdgcn_mfma_f32_16x16x32_bf16(kf0, qf[s][0], z, 0, 0, 0);
      st = __builtin_amdgcn_mfma_f32_16x16x32_bf16(kf1, qf[s][1], st, 0, 0, 0);
      union { bf16_t hh[4]; short4v s4; } u;
      for (int r = 0; r < 4; ++r) {
        float p = __builtin_amdgcn_exp2f(st[r]);   // Q pre-scaled by CEXP
        lp[s][r] += p;
        u.hh[r] = (bf16_t)p;
      }
      pB[s] = u.s4;
    }

    for (int db = 0; db < 4; ++db)
      for (int s = 0; s < 2; ++s)
        accO[s][db] = MFMA_PV(vf[db], pB[s], accO[s][db]);

    krow += 16 * 3072;
    vrow += 16;
  }

  for (int s = 0; s < 2; ++s) {
    float l = (lp[s][0] + lp[s][1]) + (lp[s][2] + lp[s][3]);
    l += __shfl_xor(l, 16);
    l += __shfl_xor(l, 32);
    float inv = 1.f / l;
    size_t tok = (size_t)b * SEQ + qw + s * 16 + l16;
    for (int db = 0; db < 4; ++db) {
      bf16_t o4[4];
      for (int r = 0; r < 4; ++r) o4[r] = (bf16_t)(accO[s][db][r] * inv);
      *(uint2*)&attn[tok * DMODEL + h * HD + db * 16 + quad * 4] = *(uint2*)o4;
    }
  }
}

// ------------------------------------------------------------- launch
extern "C" void kernel_launch(void* const* d_in, const int* in_sizes, int n_in,
                              void* d_out, int out_size, void* d_ws, size_t ws_size,
                              hipStream_t stream) {
  const void* x     = d_in[0];
  const void* w_qkv = d_in[1];
  const void* b_qkv = d_in[2];
  const void* w_out = d_in[3];
  const void* b_out = d_in[4];

  char* ws = (char*)d_ws;
  int*    flag  = (int*)ws;                                    // @0
  bf16_t* wqkvT = (bf16_t*)(ws + 4096);                        // 6.0 MB
  bf16_t* woutT = (bf16_t*)(ws + 6295552);                     // 2.0 MB
  float*  bqkvf = (float*)(ws + 8392704);
  float*  boutf = (float*)(ws + 8404992);
  bf16_t* qkv   = (bf16_t*)(ws + 8409088);                     // 8192x3072 bf16 (50.3 MB)
  bf16_t* xb    = (bf16_t*)(ws + 58740736);                    // 16.8 MB
  bf16_t* attn  = xb;                                          // alias (xb dead after gemm1)
  bf16_t* vTbuf = (bf16_t*)(ws + 75517952);                    // 16.8 MB -> end ~92.3 MB

  sniff_dtype<<<1, 256, 0, stream>>>((const uint4*)x, flag);

  conv_to_bf16<<<NOUT / 2048, 256, 0, stream>>>(x, xb, NOUT, flag);
  conv_biases<<<16, 256, 0, stream>>>(b_qkv, b_out, bqkvf, boutf, flag);

  transpose_w<<<dim3(96, 32), 256, 0, stream>>>(w_qkv, wqkvT, 1024, 3072, flag);
  transpose_w<<<dim3(32, 32), 256, 0, stream>>>(w_out, woutT, 1024, 1024, flag);

  gemm_bt_bias<2><<<dim3(24, 64), 256, 0, stream>>>(
      xb, wqkvT, bqkvf, qkv, NTOK, 3072, 1024, flag, vTbuf);

  attention_v11<<<dim3(BATCH * NH, SEQ / 256), 512, 0, stream>>>(qkv, vTbuf, attn);

  gemm_bt_bias<1><<<dim3(8, 64), 256, 0, stream>>>(
      attn, woutT, boutf, d_out, NTOK, 1024, 1024, flag, nullptr);
}

// Round 4
// 302.228 us; speedup vs baseline: 1.8072x; 1.8072x over previous
//
#include <hip/hip_runtime.h>
#include <hip/hip_bf16.h>

// MHA forward. B=4, T=2048, D=1024, H=16, Hd=64. Inputs auto-detected f32/bf16.
// convert x -> fused convert+transpose weights -> QKV GEMM(+bias; Q pre-scaled by
// log2e/8; V written transposed to vT in-epilogue) -> flash attention v9
// (double-buffered K/V LDS, ONE barrier/tile, 8 waves x 32 q/wave, reg-direct PV)
// -> out GEMM(+bias, dtype-dynamic d_out). GEMMs: 2-phase dbuf K-loop with
// counted vmcnt (T3-minimum) + bijective XCD swizzle.
// R4: never cap occupancy via __launch_bounds__ 2nd arg (spill disaster).
// R5: don't interleave P LDS writes into PV chain. R6: keep S live range to one kb.
// R7: all single-buffer variants stall ~120us on per-tile barrier drain.
// R8: v8 latency-bound at 2 waves/SIMD; v9 512-thr 32q/wave -> 4 waves/SIMD (101us).
// R9: v10 manual pipeline+stagger+setprio REGRESSED (127us): manual ordering
//     defeats compiler sched (m141); barrier re-syncs waves, stagger can't help.
// R10: v11 no-LDS direct-global attention REGRESSED 3.5x (357us, Mfma 12): K-row
//     stride 6KB -> each wave load = 16 cache lines; L1/TA issue serializes.
//     LDS staging IS the coalescer for transpose-shaped K/V access. Keep v9.
// R11 (this round): GEMMs ~130us combined > attention. Old gemm = stage;
//     syncthreads(full vmcnt0 drain); compute — the documented ~20% m97 stall.
//     New: dbuf LDS, prefetch next tile BEFORE compute, s_waitcnt vmcnt(4) +
//     raw s_barrier (in-flight prefetch never drained).

typedef __bf16 bf16_t;
typedef __bf16 bf16x8 __attribute__((ext_vector_type(8)));
typedef float f32x4 __attribute__((ext_vector_type(4)));
typedef short short4v __attribute__((ext_vector_type(4)));

#if __has_builtin(__builtin_amdgcn_mfma_f32_16x16x16_bf16)
typedef __bf16 bf16x4 __attribute__((ext_vector_type(4)));
#define MFMA_PV(va, vb, c) __builtin_amdgcn_mfma_f32_16x16x16_bf16( \
    __builtin_bit_cast(bf16x4, (va)), __builtin_bit_cast(bf16x4, (vb)), (c), 0, 0, 0)
#else
#define MFMA_PV(va, vb, c) __builtin_amdgcn_mfma_f32_16x16x16bf16_1k((va), (vb), (c), 0, 0, 0)
#endif

#define DMODEL 1024
#define NH     16
#define HD     64
#define BATCH  4
#define SEQ    2048
#define NTOK   (BATCH * SEQ)      // 8192
#define NOUT   (NTOK * DMODEL)    // 8388608
#define CEXP   0.1803368801111204f   // log2(e)/sqrt(64)

__device__ __forceinline__ void async_ld16(void* lds, const void* g) {
  __builtin_amdgcn_global_load_lds(
      (const __attribute__((address_space(1))) void*)g,
      (__attribute__((address_space(3))) void*)lds, 16, 0, 0);
}

// ------------------------------------------------------------- dtype sniff
// 8192 u16 samples via vectorized loads; f32 data -> ~32 NaN-pattern low halves.
__global__ __launch_bounds__(256) void sniff_dtype(
    const uint4* __restrict__ x, int* __restrict__ flag) {
  int t = threadIdx.x;
  uint4 v = x[t];   // 8 u16 per thread x 256 = 2048... use 4 loads
  int nanish = 0, zc = 0;
  for (int j = 0; j < 4; ++j) {
    uint4 w = x[t + j * 256];
    unsigned u[4] = {w.x, w.y, w.z, w.w};
    for (int k = 0; k < 4; ++k) {
      unsigned lo = u[k] & 0xFFFFu, hi = u[k] >> 16;
      if ((lo & 0x7F80u) == 0x7F80u) nanish++;
      if ((hi & 0x7F80u) == 0x7F80u) nanish++;
      if (lo == 0) zc++;
      if (hi == 0) zc++;
    }
  }
  (void)v;
  __shared__ int rn[256], rz[256];
  rn[t] = nanish; rz[t] = zc;
  __syncthreads();
  for (int s = 128; s > 0; s >>= 1) {
    if (t < s) { rn[t] += rn[t + s]; rz[t] += rz[t + s]; }
    __syncthreads();
  }
  if (t == 0) flag[0] = (rn[0] > 4 || rz[0] > 2048) ? 1 : 0;  // 1 = f32 inputs
}

// ------------------------------------------------------------- converters
__global__ __launch_bounds__(256) void conv_to_bf16(
    const void* __restrict__ src, bf16_t* __restrict__ dst, int n,
    const int* __restrict__ flag) {
  int i = (blockIdx.x * 256 + threadIdx.x) * 8;
  if (i >= n) return;
  if (flag[0]) {
    const float4* s = (const float4*)((const float*)src + i);
    float4 a = s[0], b = s[1];
    bf16_t* o = dst + i;
    o[0] = (bf16_t)a.x; o[1] = (bf16_t)a.y; o[2] = (bf16_t)a.z; o[3] = (bf16_t)a.w;
    o[4] = (bf16_t)b.x; o[5] = (bf16_t)b.y; o[6] = (bf16_t)b.z; o[7] = (bf16_t)b.w;
  } else {
    *(uint4*)(dst + i) = *(const uint4*)((const bf16_t*)src + i);
  }
}

__global__ __launch_bounds__(256) void conv_biases(
    const void* __restrict__ sq, const void* __restrict__ so,
    float* __restrict__ dq, float* __restrict__ dofs,
    const int* __restrict__ flag) {
  int i = blockIdx.x * 256 + threadIdx.x;
  if (i < 3072)
    dq[i] = flag[0] ? ((const float*)sq)[i] : (float)((const bf16_t*)sq)[i];
  else {
    int j = i - 3072;
    dofs[j] = flag[0] ? ((const float*)so)[j] : (float)((const bf16_t*)so)[j];
  }
}

// ------------------------------------------------------------- weight transpose
__global__ __launch_bounds__(256) void transpose_w(
    const void* __restrict__ in, bf16_t* __restrict__ out, int R, int C,
    const int* __restrict__ flag) {
  __shared__ bf16_t tile[32][33];
  const int tx = threadIdx.x & 31, ty = threadIdx.x >> 5;
  const int c0 = blockIdx.x * 32, r0 = blockIdx.y * 32;
  if (flag[0]) {
    for (int i = 0; i < 4; ++i) {
      int r = ty + i * 8;
      tile[r][tx] = (bf16_t)((const float*)in)[(size_t)(r0 + r) * C + c0 + tx];
    }
  } else {
    for (int i = 0; i < 4; ++i) {
      int r = ty + i * 8;
      tile[r][tx] = ((const bf16_t*)in)[(size_t)(r0 + r) * C + c0 + tx];
    }
  }
  __syncthreads();
  for (int i = 0; i < 4; ++i) {
    int r = ty + i * 8;
    out[(size_t)(c0 + r) * R + r0 + tx] = tile[tx][r];
  }
}

// ------------------------------------------------------------- GEMM (B^T) + f32 bias
// MODE 1: dyn f32/bf16 per flag. MODE 2: QKV epilogue — Q cols (<1024) scaled by
// CEXP; V cols (>=2048) written transposed into vT[b][h][d][seq]; K cols plain.
// Grid XCD-swizzled (bijective; both grids %8==0). K-loop: 2-phase LDS double
// buffer, next tile prefetched BEFORE compute, counted s_waitcnt vmcnt(4) + raw
// s_barrier (never drains the in-flight prefetch; T3-minimum recipe).
template <int MODE>
__global__ __launch_bounds__(256) void gemm_bt_bias(
    const bf16_t* __restrict__ A, const bf16_t* __restrict__ Bt,
    const float* __restrict__ bias, void* __restrict__ Cout,
    int M, int N, int K, const int* __restrict__ flag,
    bf16_t* __restrict__ vT) {
  __shared__ bf16_t sA[2][128 * 32];
  __shared__ bf16_t sB[2][128 * 32];
  const int t = threadIdx.x;
  const int wave = t >> 6, lane = t & 63;
  const int quad = lane >> 4, l16 = lane & 15;
  // XCD-aware bijective remap: consecutive new ids stay on one XCD's L2.
  const int nwg = gridDim.x * gridDim.y;
  const int lin = blockIdx.y * gridDim.x + blockIdx.x;
  const int cpx = nwg >> 3;                    // nwg % 8 == 0 for our grids
  const int swz = (lin & 7) * cpx + (lin >> 3);
  const int bx = swz % gridDim.x, by = swz / gridDim.x;
  const int bM = by * 128, bN = bx * 128;
  const int m0w = (wave >> 1) * 64, n0w = (wave & 1) * 64;
  const int rowS = wave * 16 + (lane >> 2);
  const int kcS = (lane & 3) * 8;

  f32x4 acc[4][4] = {};

  // 4 async_ld16 per thread per stage (2 A-rows + 2 B-rows).
  auto stage = [&](int buf, int k0) {
    for (int r = 0; r < 2; ++r) {
      int row = r * 64 + rowS;
      async_ld16((char*)sA[buf] + r * 4096 + wave * 1024,
                 A + (size_t)(bM + row) * K + k0 + kcS);
      async_ld16((char*)sB[buf] + r * 4096 + wave * 1024,
                 Bt + (size_t)(bN + row) * K + k0 + kcS);
    }
  };

  const int nsteps = K >> 5;
  stage(0, 0);

  for (int s = 0; s < nsteps; ++s) {
    const int cur = s & 1;
    if (s + 1 < nsteps) {
      stage(cur ^ 1, (s + 1) << 5);            // prefetch next tile first
      asm volatile("s_waitcnt vmcnt(4)" ::: "memory");  // wait current 4 only
    } else {
      asm volatile("s_waitcnt vmcnt(0)" ::: "memory");
    }
    __builtin_amdgcn_s_barrier();              // publish current tile
    asm volatile("" ::: "memory");

    bf16x8 af[4], bfr[4];
    for (int i = 0; i < 4; ++i)
      af[i] = *(const bf16x8*)&sA[cur][(m0w + i * 16 + l16) * 32 + quad * 8];
    for (int j = 0; j < 4; ++j)
      bfr[j] = *(const bf16x8*)&sB[cur][(n0w + j * 16 + l16) * 32 + quad * 8];
    for (int i = 0; i < 4; ++i)
      for (int j = 0; j < 4; ++j)
        acc[i][j] = __builtin_amdgcn_mfma_f32_16x16x32_bf16(af[i], bfr[j], acc[i][j], 0, 0, 0);

    asm volatile("" ::: "memory");
    __builtin_amdgcn_s_barrier();              // all reads of cur done ->
  }                                            // next iter may restage cur

  const bool f32out = (MODE == 1) && flag[0];
  for (int j = 0; j < 4; ++j) {
    int col = bN + n0w + j * 16 + l16;
    float bv = bias[col];
    for (int i = 0; i < 4; ++i) {
      int row0 = bM + m0w + i * 16 + quad * 4;
      if (MODE == 2 && col >= 2048) {
        // V column -> vT[b][h][d][s], 4 consecutive tokens packed (8B store)
        int hh = (col - 2048) >> 6, dd = (col - 2048) & 63;
        bf16_t o4[4];
        for (int r = 0; r < 4; ++r) o4[r] = (bf16_t)(acc[i][j][r] + bv);
        size_t dst = ((((size_t)(row0 >> 11) * NH + hh) * HD + dd) << 11) | (row0 & 2047);
        *(uint2*)&vT[dst] = *(uint2*)o4;
      } else {
        float scale = (MODE == 2 && col < 1024) ? CEXP : 1.0f;
        for (int r = 0; r < 4; ++r) {
          float v = (acc[i][j][r] + bv) * scale;
          if (f32out) ((float*)Cout)[(size_t)(row0 + r) * N + col] = v;
          else        ((bf16_t*)Cout)[(size_t)(row0 + r) * N + col] = (bf16_t)v;
        }
      }
    }
  }
}

// ------------------------------------------------------------- flash attention v9
// Grid (bh=64, SEQ/256=8) = 512 blocks x 512 thr = 2 blocks/CU (LDS 64 KB dbuf)
// = 16 waves/CU = 4 waves/SIMD (v8 was 2/SIMD -> latency-bound).
// Wave owns 32 q (2 subtiles). kb-outer; S^T via 16x16x32 (Q pre-scaled by CEXP
// in gemm1); exp2 direct; PV via 16x16x16 (B operand == S^T C-layout) from regs.
// K/V double-buffered: prefetch tile t+1 right after the barrier publishing t,
// compute covers the DMA latency -> ONE barrier per tile, no drain stall.
// lp kept as f32x4 (4 independent partial-sum chains; v9 had a 32-long serial add).
__global__ __launch_bounds__(512) void attention_v9(
    const bf16_t* __restrict__ qkv, const bf16_t* __restrict__ vT,
    bf16_t* __restrict__ attn) {
  const int t = threadIdx.x;
  const int wave = t >> 6, lane = t & 63;           // wave 0..7
  const int quad = lane >> 4, l16 = lane & 15;
  const int bh = blockIdx.x, b = bh >> 4, h = bh & 15;
  const int qw = blockIdx.y * 256 + wave * 32;

  __shared__ bf16_t Kt[2][128 * 64];   // [key][d], 16B-chunk XOR swizzle by key&7
  __shared__ bf16_t Vt[2][64 * 128];   // [d][key], 16B-chunk XOR swizzle by d&15

  const bf16_t* qglob = qkv + (size_t)b * SEQ * 3072 + h * 64;
  const bf16_t* kglob = qglob + 1024;
  const bf16_t* vglob = vT + (size_t)bh * HD * SEQ;

  bf16x8 qf[2][2];
  for (int s = 0; s < 2; ++s) {
    const bf16_t* qrow = qglob + (size_t)(qw + s * 16 + l16) * 3072 + quad * 8;
    qf[s][0] = *(const bf16x8*)qrow;
    qf[s][1] = *(const bf16x8*)(qrow + 32);
  }

  f32x4 accO[2][4] = {};
  f32x4 lp[2] = {};               // 4 independent partial-sum chains per subtile

  const int kRow = lane >> 3, kSlot = lane & 7;
  const int vRow = lane >> 4, vSlot = lane & 15;

  auto stageKV = [&](int buf, int kt) {
    for (int j = 0; j < 2; ++j) {   // K: wave stages keys [wave*16, +16)
      int keyl = wave * 16 + j * 8 + kRow;
      int gc = kSlot ^ (keyl & 7);
      async_ld16((char*)Kt[buf] + (wave * 16 + j * 8) * 128,
                 kglob + (size_t)(kt + keyl) * 3072 + gc * 8);
    }
    for (int j = 0; j < 2; ++j) {   // V: wave stages d [wave*8, +8)
      int d = wave * 8 + j * 4 + vRow;
      int gc = vSlot ^ (d & 15);
      async_ld16((char*)Vt[buf] + (wave * 8 + j * 4) * 256,
                 vglob + (size_t)d * SEQ + kt + gc * 8);
    }
  };

  stageKV(0, 0);

  for (int ti = 0; ti < SEQ / 128; ++ti) {
    const int buf = ti & 1;
    __syncthreads();                       // drain this tile's DMA + publish
    if (ti + 1 < SEQ / 128) stageKV(buf ^ 1, (ti + 1) * 128);

    const bf16_t* KtB = Kt[buf];
    const bf16_t* VtB = Vt[buf];

    for (int kb = 0; kb < 8; ++kb) {
      const bf16_t* kr = &KtB[(kb * 16 + l16) * 64];
      bf16x8 kf0 = *(const bf16x8*)(kr + ((quad ^ (l16 & 7)) * 8));
      bf16x8 kf1 = *(const bf16x8*)(kr + (((4 + quad) ^ (l16 & 7)) * 8));

      short4v pB[2];
      for (int s = 0; s < 2; ++s) {
        f32x4 z = {0.f, 0.f, 0.f, 0.f};
        f32x4 st = __builtin_amdgcn_mfma_f32_16x16x32_bf16(kf0, qf[s][0], z, 0, 0, 0);
        st = __builtin_amdgcn_mfma_f32_16x16x32_bf16(kf1, qf[s][1], st, 0, 0, 0);
        union { bf16_t hh[4]; short4v s4; } u;
        for (int r = 0; r < 4; ++r) {
          float p = __builtin_amdgcn_exp2f(st[r]);   // Q pre-scaled by CEXP
          lp[s][r] += p;
          u.hh[r] = (bf16_t)p;
        }
        pB[s] = u.s4;
      }

      const int chunkbase = kb * 2 + (quad >> 1);
      const int coff = (quad & 1) * 4;
      for (int db = 0; db < 4; ++db) {
        short4v vf = *(const short4v*)&VtB[(db * 16 + l16) * 128 +
                                           ((chunkbase ^ l16) * 8) + coff];
        for (int s = 0; s < 2; ++s)
          accO[s][db] = MFMA_PV(vf, pB[s], accO[s][db]);
      }
    }
  }

  for (int s = 0; s < 2; ++s) {
    float l = (lp[s][0] + lp[s][1]) + (lp[s][2] + lp[s][3]);
    l += __shfl_xor(l, 16);
    l += __shfl_xor(l, 32);
    float inv = 1.f / l;
    size_t tok = (size_t)b * SEQ + qw + s * 16 + l16;
    for (int db = 0; db < 4; ++db) {
      bf16_t o4[4];
      for (int r = 0; r < 4; ++r) o4[r] = (bf16_t)(accO[s][db][r] * inv);
      *(uint2*)&attn[tok * DMODEL + h * HD + db * 16 + quad * 4] = *(uint2*)o4;
    }
  }
}

// ------------------------------------------------------------- launch
extern "C" void kernel_launch(void* const* d_in, const int* in_sizes, int n_in,
                              void* d_out, int out_size, void* d_ws, size_t ws_size,
                              hipStream_t stream) {
  const void* x     = d_in[0];
  const void* w_qkv = d_in[1];
  const void* b_qkv = d_in[2];
  const void* w_out = d_in[3];
  const void* b_out = d_in[4];

  char* ws = (char*)d_ws;
  int*    flag  = (int*)ws;                                    // @0
  bf16_t* wqkvT = (bf16_t*)(ws + 4096);                        // 6.0 MB
  bf16_t* woutT = (bf16_t*)(ws + 6295552);                     // 2.0 MB
  float*  bqkvf = (float*)(ws + 8392704);
  float*  boutf = (float*)(ws + 8404992);
  bf16_t* qkv   = (bf16_t*)(ws + 8409088);                     // 8192x3072 bf16 (50.3 MB)
  bf16_t* xb    = (bf16_t*)(ws + 58740736);                    // 16.8 MB
  bf16_t* attn  = xb;                                          // alias (xb dead after gemm1)
  bf16_t* vTbuf = (bf16_t*)(ws + 75517952);                    // 16.8 MB -> end ~92.3 MB

  sniff_dtype<<<1, 256, 0, stream>>>((const uint4*)x, flag);

  conv_to_bf16<<<NOUT / 2048, 256, 0, stream>>>(x, xb, NOUT, flag);
  conv_biases<<<16, 256, 0, stream>>>(b_qkv, b_out, bqkvf, boutf, flag);

  transpose_w<<<dim3(96, 32), 256, 0, stream>>>(w_qkv, wqkvT, 1024, 3072, flag);
  transpose_w<<<dim3(32, 32), 256, 0, stream>>>(w_out, woutT, 1024, 1024, flag);

  gemm_bt_bias<2><<<dim3(24, 64), 256, 0, stream>>>(
      xb, wqkvT, bqkvf, qkv, NTOK, 3072, 1024, flag, vTbuf);

  attention_v9<<<dim3(BATCH * NH, SEQ / 256), 512, 0, stream>>>(qkv, vTbuf, attn);

  gemm_bt_bias<1><<<dim3(8, 64), 256, 0, stream>>>(
      attn, woutT, boutf, d_out, NTOK, 1024, 1024, flag, nullptr);
}

// Round 5
// 298.853 us; speedup vs baseline: 1.8276x; 1.0113x over previous
//
#include <hip/hip_runtime.h>
#include <hip/hip_bf16.h>

// MHA forward. B=4, T=2048, D=1024, H=16, Hd=64. Inputs auto-detected f32/bf16.
// convert x -> fused convert+transpose weights -> QKV GEMM(+bias; Q pre-scaled by
// log2e/8; V written transposed to vT in-epilogue) -> flash attention v9
// (double-buffered K/V LDS, ONE barrier/tile, 8 waves x 32 q/wave, reg-direct PV)
// -> out GEMM(+bias, dtype-dynamic d_out). GEMMs: depth-2 prefetch (triple-buf
// LDS) K-loop with counted vmcnt + bijective XCD swizzle.
// R4: never cap occupancy via __launch_bounds__ 2nd arg (spill disaster).
// R5: don't interleave P LDS writes into PV chain. R6: keep S live range to one kb.
// R7: all single-buffer variants stall ~120us on per-tile barrier drain.
// R8: v8 latency-bound at 2 waves/SIMD; v9 512-thr 32q/wave -> 4 waves/SIMD (101us).
// R9: v10 manual pipeline+stagger+setprio REGRESSED (127us): manual ordering
//     defeats compiler sched (m141); barrier re-syncs waves, stagger can't help.
// R10: v11 no-LDS direct-global attention REGRESSED 3.5x (357us, Mfma 12): K-row
//     stride 6KB -> each wave load = 16 cache lines; L1/TA issue serializes.
//     LDS staging IS the coalescer for transpose-shaped K/V access. Keep v9.
// R11: gemm 2-phase counted-vmcnt dbuf: ~ -6us net on GEMMs. Keep + deepen.
// R12: lp-as-f32x4 in attention REGRESSED 101->114us (VGPR 88->84, Mfma 43->36):
//     accumulator vectorization perturbed regalloc/schedule. Scalar lpart is the
//     verified form — do NOT touch attention accumulators without in-situ A/B.
// R13 (this round): gemm prefetch depth 1 -> 2 (triple-buffer, 48KB LDS, still
//     3 blocks/CU which is the VGPR limit). stage(s) now issued two compute
//     phases before its vmcnt wait (~2x latency cover).

typedef __bf16 bf16_t;
typedef __bf16 bf16x8 __attribute__((ext_vector_type(8)));
typedef float f32x4 __attribute__((ext_vector_type(4)));
typedef short short4v __attribute__((ext_vector_type(4)));

#if __has_builtin(__builtin_amdgcn_mfma_f32_16x16x16_bf16)
typedef __bf16 bf16x4 __attribute__((ext_vector_type(4)));
#define MFMA_PV(va, vb, c) __builtin_amdgcn_mfma_f32_16x16x16_bf16( \
    __builtin_bit_cast(bf16x4, (va)), __builtin_bit_cast(bf16x4, (vb)), (c), 0, 0, 0)
#else
#define MFMA_PV(va, vb, c) __builtin_amdgcn_mfma_f32_16x16x16bf16_1k((va), (vb), (c), 0, 0, 0)
#endif

#define DMODEL 1024
#define NH     16
#define HD     64
#define BATCH  4
#define SEQ    2048
#define NTOK   (BATCH * SEQ)      // 8192
#define NOUT   (NTOK * DMODEL)    // 8388608
#define CEXP   0.1803368801111204f   // log2(e)/sqrt(64)

__device__ __forceinline__ void async_ld16(void* lds, const void* g) {
  __builtin_amdgcn_global_load_lds(
      (const __attribute__((address_space(1))) void*)g,
      (__attribute__((address_space(3))) void*)lds, 16, 0, 0);
}

// ------------------------------------------------------------- dtype sniff
// 8192 u16 samples via vectorized loads; f32 data -> ~32 NaN-pattern low halves.
__global__ __launch_bounds__(256) void sniff_dtype(
    const uint4* __restrict__ x, int* __restrict__ flag) {
  int t = threadIdx.x;
  uint4 v = x[t];   // 8 u16 per thread x 256 = 2048... use 4 loads
  int nanish = 0, zc = 0;
  for (int j = 0; j < 4; ++j) {
    uint4 w = x[t + j * 256];
    unsigned u[4] = {w.x, w.y, w.z, w.w};
    for (int k = 0; k < 4; ++k) {
      unsigned lo = u[k] & 0xFFFFu, hi = u[k] >> 16;
      if ((lo & 0x7F80u) == 0x7F80u) nanish++;
      if ((hi & 0x7F80u) == 0x7F80u) nanish++;
      if (lo == 0) zc++;
      if (hi == 0) zc++;
    }
  }
  (void)v;
  __shared__ int rn[256], rz[256];
  rn[t] = nanish; rz[t] = zc;
  __syncthreads();
  for (int s = 128; s > 0; s >>= 1) {
    if (t < s) { rn[t] += rn[t + s]; rz[t] += rz[t + s]; }
    __syncthreads();
  }
  if (t == 0) flag[0] = (rn[0] > 4 || rz[0] > 2048) ? 1 : 0;  // 1 = f32 inputs
}

// ------------------------------------------------------------- converters
__global__ __launch_bounds__(256) void conv_to_bf16(
    const void* __restrict__ src, bf16_t* __restrict__ dst, int n,
    const int* __restrict__ flag) {
  int i = (blockIdx.x * 256 + threadIdx.x) * 8;
  if (i >= n) return;
  if (flag[0]) {
    const float4* s = (const float4*)((const float*)src + i);
    float4 a = s[0], b = s[1];
    bf16_t* o = dst + i;
    o[0] = (bf16_t)a.x; o[1] = (bf16_t)a.y; o[2] = (bf16_t)a.z; o[3] = (bf16_t)a.w;
    o[4] = (bf16_t)b.x; o[5] = (bf16_t)b.y; o[6] = (bf16_t)b.z; o[7] = (bf16_t)b.w;
  } else {
    *(uint4*)(dst + i) = *(const uint4*)((const bf16_t*)src + i);
  }
}

__global__ __launch_bounds__(256) void conv_biases(
    const void* __restrict__ sq, const void* __restrict__ so,
    float* __restrict__ dq, float* __restrict__ dofs,
    const int* __restrict__ flag) {
  int i = blockIdx.x * 256 + threadIdx.x;
  if (i < 3072)
    dq[i] = flag[0] ? ((const float*)sq)[i] : (float)((const bf16_t*)sq)[i];
  else {
    int j = i - 3072;
    dofs[j] = flag[0] ? ((const float*)so)[j] : (float)((const bf16_t*)so)[j];
  }
}

// ------------------------------------------------------------- weight transpose
__global__ __launch_bounds__(256) void transpose_w(
    const void* __restrict__ in, bf16_t* __restrict__ out, int R, int C,
    const int* __restrict__ flag) {
  __shared__ bf16_t tile[32][33];
  const int tx = threadIdx.x & 31, ty = threadIdx.x >> 5;
  const int c0 = blockIdx.x * 32, r0 = blockIdx.y * 32;
  if (flag[0]) {
    for (int i = 0; i < 4; ++i) {
      int r = ty + i * 8;
      tile[r][tx] = (bf16_t)((const float*)in)[(size_t)(r0 + r) * C + c0 + tx];
    }
  } else {
    for (int i = 0; i < 4; ++i) {
      int r = ty + i * 8;
      tile[r][tx] = ((const bf16_t*)in)[(size_t)(r0 + r) * C + c0 + tx];
    }
  }
  __syncthreads();
  for (int i = 0; i < 4; ++i) {
    int r = ty + i * 8;
    out[(size_t)(c0 + r) * R + r0 + tx] = tile[tx][r];
  }
}

// ------------------------------------------------------------- GEMM (B^T) + f32 bias
// MODE 1: dyn f32/bf16 per flag. MODE 2: QKV epilogue — Q cols (<1024) scaled by
// CEXP; V cols (>=2048) written transposed into vT[b][h][d][seq]; K cols plain.
// Grid XCD-swizzled (bijective; both grids %8==0). K-loop: depth-2 prefetch into
// triple-buffered LDS; counted s_waitcnt vmcnt(8) + raw s_barrier (stage(s)
// issued two compute phases before its wait; in-flight prefetch never drained).
// Race-safety: stage(s+2) overwrites buf (s-1)%3, protected by step s-1's end
// barrier; every wave vmcnt-waits its own loads before the publish barrier.
template <int MODE>
__global__ __launch_bounds__(256) void gemm_bt_bias(
    const bf16_t* __restrict__ A, const bf16_t* __restrict__ Bt,
    const float* __restrict__ bias, void* __restrict__ Cout,
    int M, int N, int K, const int* __restrict__ flag,
    bf16_t* __restrict__ vT) {
  __shared__ bf16_t sA[3][128 * 32];
  __shared__ bf16_t sB[3][128 * 32];
  const int t = threadIdx.x;
  const int wave = t >> 6, lane = t & 63;
  const int quad = lane >> 4, l16 = lane & 15;
  // XCD-aware bijective remap: consecutive new ids stay on one XCD's L2.
  const int nwg = gridDim.x * gridDim.y;
  const int lin = blockIdx.y * gridDim.x + blockIdx.x;
  const int cpx = nwg >> 3;                    // nwg % 8 == 0 for our grids
  const int swz = (lin & 7) * cpx + (lin >> 3);
  const int bx = swz % gridDim.x, by = swz / gridDim.x;
  const int bM = by * 128, bN = bx * 128;
  const int m0w = (wave >> 1) * 64, n0w = (wave & 1) * 64;
  const int rowS = wave * 16 + (lane >> 2);
  const int kcS = (lane & 3) * 8;

  f32x4 acc[4][4] = {};

  // 4 async_ld16 per thread per stage (2 A-rows + 2 B-rows).
  auto stage = [&](int buf, int k0) {
    for (int r = 0; r < 2; ++r) {
      int row = r * 64 + rowS;
      async_ld16((char*)sA[buf] + r * 4096 + wave * 1024,
                 A + (size_t)(bM + row) * K + k0 + kcS);
      async_ld16((char*)sB[buf] + r * 4096 + wave * 1024,
                 Bt + (size_t)(bN + row) * K + k0 + kcS);
    }
  };

  const int nsteps = K >> 5;                   // 32 for K=1024
  stage(0, 0);
  stage(1, 32);

  for (int s = 0; s < nsteps; ++s) {
    const int cur = s % 3;
    if (s + 2 < nsteps) {
      stage((s + 2) % 3, (s + 2) << 5);        // prefetch 2 tiles ahead
      asm volatile("s_waitcnt vmcnt(8)" ::: "memory");  // stage(s) done
    } else if (s + 1 < nsteps) {
      asm volatile("s_waitcnt vmcnt(4)" ::: "memory");
    } else {
      asm volatile("s_waitcnt vmcnt(0)" ::: "memory");
    }
    __builtin_amdgcn_s_barrier();              // publish current tile
    asm volatile("" ::: "memory");

    bf16x8 af[4], bfr[4];
    for (int i = 0; i < 4; ++i)
      af[i] = *(const bf16x8*)&sA[cur][(m0w + i * 16 + l16) * 32 + quad * 8];
    for (int j = 0; j < 4; ++j)
      bfr[j] = *(const bf16x8*)&sB[cur][(n0w + j * 16 + l16) * 32 + quad * 8];
    for (int i = 0; i < 4; ++i)
      for (int j = 0; j < 4; ++j)
        acc[i][j] = __builtin_amdgcn_mfma_f32_16x16x32_bf16(af[i], bfr[j], acc[i][j], 0, 0, 0);

    asm volatile("" ::: "memory");
    __builtin_amdgcn_s_barrier();              // all reads of cur done ->
  }                                            // buf cur may be restaged

  const bool f32out = (MODE == 1) && flag[0];
  for (int j = 0; j < 4; ++j) {
    int col = bN + n0w + j * 16 + l16;
    float bv = bias[col];
    for (int i = 0; i < 4; ++i) {
      int row0 = bM + m0w + i * 16 + quad * 4;
      if (MODE == 2 && col >= 2048) {
        // V column -> vT[b][h][d][s], 4 consecutive tokens packed (8B store)
        int hh = (col - 2048) >> 6, dd = (col - 2048) & 63;
        bf16_t o4[4];
        for (int r = 0; r < 4; ++r) o4[r] = (bf16_t)(acc[i][j][r] + bv);
        size_t dst = ((((size_t)(row0 >> 11) * NH + hh) * HD + dd) << 11) | (row0 & 2047);
        *(uint2*)&vT[dst] = *(uint2*)o4;
      } else {
        float scale = (MODE == 2 && col < 1024) ? CEXP : 1.0f;
        for (int r = 0; r < 4; ++r) {
          float v = (acc[i][j][r] + bv) * scale;
          if (f32out) ((float*)Cout)[(size_t)(row0 + r) * N + col] = v;
          else        ((bf16_t*)Cout)[(size_t)(row0 + r) * N + col] = (bf16_t)v;
        }
      }
    }
  }
}

// ------------------------------------------------------------- flash attention v9
// Grid (bh=64, SEQ/256=8) = 512 blocks x 512 thr = 2 blocks/CU (LDS 64 KB dbuf)
// = 16 waves/CU = 4 waves/SIMD (v8 was 2/SIMD -> latency-bound).
// Wave owns 32 q (2 subtiles). kb-outer; S^T via 16x16x32 (Q pre-scaled by CEXP
// in gemm1); exp2 direct; PV via 16x16x16 (B operand == S^T C-layout) from regs.
// K/V double-buffered: prefetch tile t+1 right after the barrier publishing t,
// compute covers the DMA latency -> ONE barrier per tile, no drain stall.
// R12: scalar lpart accumulators are load-bearing (f32x4 variant lost 13%).
__global__ __launch_bounds__(512) void attention_v9(
    const bf16_t* __restrict__ qkv, const bf16_t* __restrict__ vT,
    bf16_t* __restrict__ attn) {
  const int t = threadIdx.x;
  const int wave = t >> 6, lane = t & 63;           // wave 0..7
  const int quad = lane >> 4, l16 = lane & 15;
  const int bh = blockIdx.x, b = bh >> 4, h = bh & 15;
  const int qw = blockIdx.y * 256 + wave * 32;

  __shared__ bf16_t Kt[2][128 * 64];   // [key][d], 16B-chunk XOR swizzle by key&7
  __shared__ bf16_t Vt[2][64 * 128];   // [d][key], 16B-chunk XOR swizzle by d&15

  const bf16_t* qglob = qkv + (size_t)b * SEQ * 3072 + h * 64;
  const bf16_t* kglob = qglob + 1024;
  const bf16_t* vglob = vT + (size_t)bh * HD * SEQ;

  bf16x8 qf[2][2];
  for (int s = 0; s < 2; ++s) {
    const bf16_t* qrow = qglob + (size_t)(qw + s * 16 + l16) * 3072 + quad * 8;
    qf[s][0] = *(const bf16x8*)qrow;
    qf[s][1] = *(const bf16x8*)(qrow + 32);
  }

  f32x4 accO[2][4] = {};
  float lpart[2] = {0.f, 0.f};

  const int kRow = lane >> 3, kSlot = lane & 7;
  const int vRow = lane >> 4, vSlot = lane & 15;

  auto stageKV = [&](int buf, int kt) {
    for (int j = 0; j < 2; ++j) {   // K: wave stages keys [wave*16, +16)
      int keyl = wave * 16 + j * 8 + kRow;
      int gc = kSlot ^ (keyl & 7);
      async_ld16((char*)Kt[buf] + (wave * 16 + j * 8) * 128,
                 kglob + (size_t)(kt + keyl) * 3072 + gc * 8);
    }
    for (int j = 0; j < 2; ++j) {   // V: wave stages d [wave*8, +8)
      int d = wave * 8 + j * 4 + vRow;
      int gc = vSlot ^ (d & 15);
      async_ld16((char*)Vt[buf] + (wave * 8 + j * 4) * 256,
                 vglob + (size_t)d * SEQ + kt + gc * 8);
    }
  };

  stageKV(0, 0);

  for (int ti = 0; ti < SEQ / 128; ++ti) {
    const int buf = ti & 1;
    __syncthreads();                       // drain this tile's DMA + publish
    if (ti + 1 < SEQ / 128) stageKV(buf ^ 1, (ti + 1) * 128);

    const bf16_t* KtB = Kt[buf];
    const bf16_t* VtB = Vt[buf];

    for (int kb = 0; kb < 8; ++kb) {
      const bf16_t* kr = &KtB[(kb * 16 + l16) * 64];
      bf16x8 kf0 = *(const bf16x8*)(kr + ((quad ^ (l16 & 7)) * 8));
      bf16x8 kf1 = *(const bf16x8*)(kr + (((4 + quad) ^ (l16 & 7)) * 8));

      short4v pB[2];
      for (int s = 0; s < 2; ++s) {
        f32x4 z = {0.f, 0.f, 0.f, 0.f};
        f32x4 st = __builtin_amdgcn_mfma_f32_16x16x32_bf16(kf0, qf[s][0], z, 0, 0, 0);
        st = __builtin_amdgcn_mfma_f32_16x16x32_bf16(kf1, qf[s][1], st, 0, 0, 0);
        union { bf16_t hh[4]; short4v s4; } u;
        for (int r = 0; r < 4; ++r) {
          float p = __builtin_amdgcn_exp2f(st[r]);   // Q pre-scaled by CEXP
          lpart[s] += p;
          u.hh[r] = (bf16_t)p;
        }
        pB[s] = u.s4;
      }

      const int chunkbase = kb * 2 + (quad >> 1);
      const int coff = (quad & 1) * 4;
      for (int db = 0; db < 4; ++db) {
        short4v vf = *(const short4v*)&VtB[(db * 16 + l16) * 128 +
                                           ((chunkbase ^ l16) * 8) + coff];
        for (int s = 0; s < 2; ++s)
          accO[s][db] = MFMA_PV(vf, pB[s], accO[s][db]);
      }
    }
  }

  for (int s = 0; s < 2; ++s) {
    float l = lpart[s];
    l += __shfl_xor(l, 16);
    l += __shfl_xor(l, 32);
    float inv = 1.f / l;
    size_t tok = (size_t)b * SEQ + qw + s * 16 + l16;
    for (int db = 0; db < 4; ++db) {
      bf16_t o4[4];
      for (int r = 0; r < 4; ++r) o4[r] = (bf16_t)(accO[s][db][r] * inv);
      *(uint2*)&attn[tok * DMODEL + h * HD + db * 16 + quad * 4] = *(uint2*)o4;
    }
  }
}

// ------------------------------------------------------------- launch
extern "C" void kernel_launch(void* const* d_in, const int* in_sizes, int n_in,
                              void* d_out, int out_size, void* d_ws, size_t ws_size,
                              hipStream_t stream) {
  const void* x     = d_in[0];
  const void* w_qkv = d_in[1];
  const void* b_qkv = d_in[2];
  const void* w_out = d_in[3];
  const void* b_out = d_in[4];

  char* ws = (char*)d_ws;
  int*    flag  = (int*)ws;                                    // @0
  bf16_t* wqkvT = (bf16_t*)(ws + 4096);                        // 6.0 MB
  bf16_t* woutT = (bf16_t*)(ws + 6295552);                     // 2.0 MB
  float*  bqkvf = (float*)(ws + 8392704);
  float*  boutf = (float*)(ws + 8404992);
  bf16_t* qkv   = (bf16_t*)(ws + 8409088);                     // 8192x3072 bf16 (50.3 MB)
  bf16_t* xb    = (bf16_t*)(ws + 58740736);                    // 16.8 MB
  bf16_t* attn  = xb;                                          // alias (xb dead after gemm1)
  bf16_t* vTbuf = (bf16_t*)(ws + 75517952);                    // 16.8 MB -> end ~92.3 MB

  sniff_dtype<<<1, 256, 0, stream>>>((const uint4*)x, flag);

  conv_to_bf16<<<NOUT / 2048, 256, 0, stream>>>(x, xb, NOUT, flag);
  conv_biases<<<16, 256, 0, stream>>>(b_qkv, b_out, bqkvf, boutf, flag);

  transpose_w<<<dim3(96, 32), 256, 0, stream>>>(w_qkv, wqkvT, 1024, 3072, flag);
  transpose_w<<<dim3(32, 32), 256, 0, stream>>>(w_out, woutT, 1024, 1024, flag);

  gemm_bt_bias<2><<<dim3(24, 64), 256, 0, stream>>>(
      xb, wqkvT, bqkvf, qkv, NTOK, 3072, 1024, flag, vTbuf);

  attention_v9<<<dim3(BATCH * NH, SEQ / 256), 512, 0, stream>>>(qkv, vTbuf, attn);

  gemm_bt_bias<1><<<dim3(8, 64), 256, 0, stream>>>(
      attn, woutT, boutf, d_out, NTOK, 1024, 1024, flag, nullptr);
}

// Round 6
// 297.003 us; speedup vs baseline: 1.8390x; 1.0062x over previous
//
#include <hip/hip_runtime.h>
#include <hip/hip_bf16.h>

// MHA forward. B=4, T=2048, D=1024, H=16, Hd=64. Inputs auto-detected f32/bf16.
// convert x -> fused convert+transpose weights -> QKV GEMM (256x256 8-phase
// m201-template port, +bias; Q pre-scaled by log2e/8; V written transposed to vT
// in-epilogue) -> flash attention v9 -> out GEMM(+bias, 128^2 depth-2 dbuf).
// R4: never cap occupancy via __launch_bounds__ 2nd arg (spill disaster).
// R5: don't interleave P LDS writes into PV chain. R6: keep S live range to one kb.
// R7: all single-buffer variants stall ~120us on per-tile barrier drain.
// R8: v8 latency-bound at 2 waves/SIMD; v9 512-thr 32q/wave -> 4 waves/SIMD (101us).
// R9: v10 manual pipeline+stagger+setprio REGRESSED (127us): manual ordering
//     defeats compiler sched (m141); barrier re-syncs waves, stagger can't help.
// R10: v11 no-LDS direct-global attention REGRESSED 3.5x (357us, Mfma 12): K-row
//     stride 6KB -> each wave load = 16 cache lines; L1/TA issue serializes.
//     LDS staging IS the coalescer for transpose-shaped K/V access. Keep v9.
// R11: gemm 2-phase counted-vmcnt dbuf: ~ -6us net. R13: depth-3 neutral —
//     128^2/BK32 limiter is barrier cadence (1 barrier-pair / 16 MFMA), not depth.
// R12: lp-as-f32x4 in attention REGRESSED 101->114us: accumulator vectorization
//     perturbed regalloc. Scalar lpart is load-bearing; no attn edits w/o A/B.
// R14 (this round): gemm1 -> full 8-phase 256^2 template (T2+T3+T4+T5 co-designed;
//     2-phase grafts only gave -6us because T2/T5 are gated on the 8-phase
//     schedule). Units [256][32] XOR-swizzled; gload_lds linear dest +
//     pre-inverse-swizzled source; 1 counted vmcnt(4)/tile; unit staged exactly
//     one phase after the barrier retiring its readers. gemm2 stays 128^2
//     (256^2 grid would be 128 blocks = half chip idle).

typedef __bf16 bf16_t;
typedef __bf16 bf16x8 __attribute__((ext_vector_type(8)));
typedef float f32x4 __attribute__((ext_vector_type(4)));
typedef short short4v __attribute__((ext_vector_type(4)));

#if __has_builtin(__builtin_amdgcn_mfma_f32_16x16x16_bf16)
typedef __bf16 bf16x4 __attribute__((ext_vector_type(4)));
#define MFMA_PV(va, vb, c) __builtin_amdgcn_mfma_f32_16x16x16_bf16( \
    __builtin_bit_cast(bf16x4, (va)), __builtin_bit_cast(bf16x4, (vb)), (c), 0, 0, 0)
#else
#define MFMA_PV(va, vb, c) __builtin_amdgcn_mfma_f32_16x16x16bf16_1k((va), (vb), (c), 0, 0, 0)
#endif

#define DMODEL 1024
#define NH     16
#define HD     64
#define BATCH  4
#define SEQ    2048
#define NTOK   (BATCH * SEQ)      // 8192
#define NOUT   (NTOK * DMODEL)    // 8388608
#define CEXP   0.1803368801111204f   // log2(e)/sqrt(64)

__device__ __forceinline__ void async_ld16(void* lds, const void* g) {
  __builtin_amdgcn_global_load_lds(
      (const __attribute__((address_space(1))) void*)g,
      (__attribute__((address_space(3))) void*)lds, 16, 0, 0);
}

// ------------------------------------------------------------- dtype sniff
// 8192 u16 samples via vectorized loads; f32 data -> ~32 NaN-pattern low halves.
__global__ __launch_bounds__(256) void sniff_dtype(
    const uint4* __restrict__ x, int* __restrict__ flag) {
  int t = threadIdx.x;
  uint4 v = x[t];
  int nanish = 0, zc = 0;
  for (int j = 0; j < 4; ++j) {
    uint4 w = x[t + j * 256];
    unsigned u[4] = {w.x, w.y, w.z, w.w};
    for (int k = 0; k < 4; ++k) {
      unsigned lo = u[k] & 0xFFFFu, hi = u[k] >> 16;
      if ((lo & 0x7F80u) == 0x7F80u) nanish++;
      if ((hi & 0x7F80u) == 0x7F80u) nanish++;
      if (lo == 0) zc++;
      if (hi == 0) zc++;
    }
  }
  (void)v;
  __shared__ int rn[256], rz[256];
  rn[t] = nanish; rz[t] = zc;
  __syncthreads();
  for (int s = 128; s > 0; s >>= 1) {
    if (t < s) { rn[t] += rn[t + s]; rz[t] += rz[t + s]; }
    __syncthreads();
  }
  if (t == 0) flag[0] = (rn[0] > 4 || rz[0] > 2048) ? 1 : 0;  // 1 = f32 inputs
}

// ------------------------------------------------------------- converters
__global__ __launch_bounds__(256) void conv_to_bf16(
    const void* __restrict__ src, bf16_t* __restrict__ dst, int n,
    const int* __restrict__ flag) {
  int i = (blockIdx.x * 256 + threadIdx.x) * 8;
  if (i >= n) return;
  if (flag[0]) {
    const float4* s = (const float4*)((const float*)src + i);
    float4 a = s[0], b = s[1];
    bf16_t* o = dst + i;
    o[0] = (bf16_t)a.x; o[1] = (bf16_t)a.y; o[2] = (bf16_t)a.z; o[3] = (bf16_t)a.w;
    o[4] = (bf16_t)b.x; o[5] = (bf16_t)b.y; o[6] = (bf16_t)b.z; o[7] = (bf16_t)b.w;
  } else {
    *(uint4*)(dst + i) = *(const uint4*)((const bf16_t*)src + i);
  }
}

__global__ __launch_bounds__(256) void conv_biases(
    const void* __restrict__ sq, const void* __restrict__ so,
    float* __restrict__ dq, float* __restrict__ dofs,
    const int* __restrict__ flag) {
  int i = blockIdx.x * 256 + threadIdx.x;
  if (i < 3072)
    dq[i] = flag[0] ? ((const float*)sq)[i] : (float)((const bf16_t*)sq)[i];
  else {
    int j = i - 3072;
    dofs[j] = flag[0] ? ((const float*)so)[j] : (float)((const bf16_t*)so)[j];
  }
}

// ------------------------------------------------------------- weight transpose
__global__ __launch_bounds__(256) void transpose_w(
    const void* __restrict__ in, bf16_t* __restrict__ out, int R, int C,
    const int* __restrict__ flag) {
  __shared__ bf16_t tile[32][33];
  const int tx = threadIdx.x & 31, ty = threadIdx.x >> 5;
  const int c0 = blockIdx.x * 32, r0 = blockIdx.y * 32;
  if (flag[0]) {
    for (int i = 0; i < 4; ++i) {
      int r = ty + i * 8;
      tile[r][tx] = (bf16_t)((const float*)in)[(size_t)(r0 + r) * C + c0 + tx];
    }
  } else {
    for (int i = 0; i < 4; ++i) {
      int r = ty + i * 8;
      tile[r][tx] = ((const bf16_t*)in)[(size_t)(r0 + r) * C + c0 + tx];
    }
  }
  __syncthreads();
  for (int i = 0; i < 4; ++i) {
    int r = ty + i * 8;
    out[(size_t)(c0 + r) * R + r0 + tx] = tile[tx][r];
  }
}

// ------------------------------------------------------------- 128^2 GEMM (B^T) + bias
// MODE 1 only (out-proj): dyn f32/bf16 per flag. 2-phase dbuf, counted vmcnt.
template <int MODE>
__global__ __launch_bounds__(256) void gemm_bt_bias(
    const bf16_t* __restrict__ A, const bf16_t* __restrict__ Bt,
    const float* __restrict__ bias, void* __restrict__ Cout,
    int M, int N, int K, const int* __restrict__ flag) {
  __shared__ bf16_t sA[2][128 * 32];
  __shared__ bf16_t sB[2][128 * 32];
  const int t = threadIdx.x;
  const int wave = t >> 6, lane = t & 63;
  const int quad = lane >> 4, l16 = lane & 15;
  const int nwg = gridDim.x * gridDim.y;
  const int lin = blockIdx.y * gridDim.x + blockIdx.x;
  const int cpx = nwg >> 3;                    // nwg % 8 == 0 for our grids
  const int swz = (lin & 7) * cpx + (lin >> 3);
  const int bx = swz % gridDim.x, by = swz / gridDim.x;
  const int bM = by * 128, bN = bx * 128;
  const int m0w = (wave >> 1) * 64, n0w = (wave & 1) * 64;
  const int rowS = wave * 16 + (lane >> 2);
  const int kcS = (lane & 3) * 8;

  f32x4 acc[4][4] = {};

  auto stage = [&](int buf, int k0) {
    for (int r = 0; r < 2; ++r) {
      int row = r * 64 + rowS;
      async_ld16((char*)sA[buf] + r * 4096 + wave * 1024,
                 A + (size_t)(bM + row) * K + k0 + kcS);
      async_ld16((char*)sB[buf] + r * 4096 + wave * 1024,
                 Bt + (size_t)(bN + row) * K + k0 + kcS);
    }
  };

  const int nsteps = K >> 5;
  stage(0, 0);

  for (int s = 0; s < nsteps; ++s) {
    const int cur = s & 1;
    if (s + 1 < nsteps) {
      stage(cur ^ 1, (s + 1) << 5);
      asm volatile("s_waitcnt vmcnt(4)" ::: "memory");
    } else {
      asm volatile("s_waitcnt vmcnt(0)" ::: "memory");
    }
    __builtin_amdgcn_s_barrier();
    asm volatile("" ::: "memory");

    bf16x8 af[4], bfr[4];
    for (int i = 0; i < 4; ++i)
      af[i] = *(const bf16x8*)&sA[cur][(m0w + i * 16 + l16) * 32 + quad * 8];
    for (int j = 0; j < 4; ++j)
      bfr[j] = *(const bf16x8*)&sB[cur][(n0w + j * 16 + l16) * 32 + quad * 8];
    for (int i = 0; i < 4; ++i)
      for (int j = 0; j < 4; ++j)
        acc[i][j] = __builtin_amdgcn_mfma_f32_16x16x32_bf16(af[i], bfr[j], acc[i][j], 0, 0, 0);

    asm volatile("" ::: "memory");
    __builtin_amdgcn_s_barrier();
  }

  const bool f32out = (MODE == 1) && flag[0];
  for (int j = 0; j < 4; ++j) {
    int col = bN + n0w + j * 16 + l16;
    float bv = bias[col];
    for (int i = 0; i < 4; ++i) {
      int row0 = bM + m0w + i * 16 + quad * 4;
      for (int r = 0; r < 4; ++r) {
        float v = acc[i][j][r] + bv;
        if (f32out) ((float*)Cout)[(size_t)(row0 + r) * N + col] = v;
        else        ((bf16_t*)Cout)[(size_t)(row0 + r) * N + col] = (bf16_t)v;
      }
    }
  }
}

// ------------------------------------------------------------- 256^2 8-phase QKV GEMM
// m201 template in plain HIP. 512 thr = 8 waves (2M x 4N); per-wave C = 128x64
// = acc[8][4] 16x16 frags. K-tile BK=64 = 4 LDS units of [256 rows][32 k] bf16
// (16KB each): U0=(A,k0) U1=(B,k0) U2=(A,k1) U3=(B,k1). 2-tile dbuf = 128KB.
// Swizzle (T2): unit byte ^= ((row&8)<<1)|((row&4)<<3) -> 2-way banks on b128
// reads (free, m136). gload_lds dest LINEAR; SOURCE pre-inverse-swizzled (m173):
// thread t stages chunk c=p*512+t, src row=c>>2, kl=((t^xr)&3)*8.
// Pipeline: tile T phases p0..p3 read {U0+U1, U0, U2+U3, U2} of buf(T); stage
// slots: p0->T+1.U2, p1->T+1.U3, p2->T+2.U0, p3->T+2.U1. Every unit is staged
// one phase AFTER the all-wave barrier retiring its last reader (p2's U0-stage
// targets the slot freed at p1.bar2) -> race-free by construction. One counted
// vmcnt(4) per tile (p3) proves tile T+1 landed with 2 units still in flight.
__global__ __launch_bounds__(512) void gemm256_qkv(
    const bf16_t* __restrict__ A, const bf16_t* __restrict__ Bt,
    const float* __restrict__ bias, bf16_t* __restrict__ Cout,
    int M, int N, int K, bf16_t* __restrict__ vT) {
  __shared__ __align__(16) char smem[131072];
  char* lds = smem;
  const int t = threadIdx.x;
  const int wave = t >> 6, lane = t & 63;
  const int quad = lane >> 4, l16 = lane & 15;
  const int wr = wave >> 2, wc = wave & 3;
  const int nwg = gridDim.x * gridDim.y;       // 384, %8==0
  const int lin = blockIdx.y * gridDim.x + blockIdx.x;
  const int cpx = nwg >> 3;
  const int swzb = (lin & 7) * cpx + (lin >> 3);
  const int bx = swzb % gridDim.x, by = swzb / gridDim.x;
  const int bM = by * 256, bN = bx * 256;

  // staging source (pre-inverse-swizzled): thread t stages chunks c = p*512+t
  const int srow = t >> 2;                       // rows 0..127 (pass0), +128 (pass1)
  const int xr = ((srow >> 3) & 1) | (((srow >> 2) & 1) << 1);
  const int skl = ((t ^ xr) & 3) * 8;
  const size_t offA0 = (size_t)(bM + srow) * K + skl;
  const size_t offB0 = (size_t)(bN + srow) * K + skl;
  const size_t off1 = (size_t)128 * K;
  const int ldsw = wave * 1024;

#define STG_A(bufo, h, k0t) do {                                               \
    async_ld16(lds + (bufo) + (h) * 16384 + ldsw, A + offA0 + (k0t) + (h) * 32);\
    async_ld16(lds + (bufo) + (h) * 16384 + 8192 + ldsw,                       \
               A + offA0 + off1 + (k0t) + (h) * 32); } while (0)
#define STG_B(bufo, h, k0t) do {                                               \
    async_ld16(lds + (bufo) + 32768 + (h) * 16384 + ldsw,                      \
               Bt + offB0 + (k0t) + (h) * 32);                                 \
    async_ld16(lds + (bufo) + 32768 + (h) * 16384 + 8192 + ldsw,               \
               Bt + offB0 + off1 + (k0t) + (h) * 32); } while (0)

  // reader byte offsets within a unit (swizzled), compile-time-indexed only
  int aoff[8], boff[4];
#pragma unroll
  for (int mf = 0; mf < 8; ++mf) {
    int r = wr * 128 + mf * 16 + l16;
    aoff[mf] = ((r << 6) + (quad << 4)) ^ (((r & 8) << 1) | ((r & 4) << 3));
  }
#pragma unroll
  for (int nf = 0; nf < 4; ++nf) {
    int r = wc * 64 + nf * 16 + l16;
    boff[nf] = 32768 + (((r << 6) + (quad << 4)) ^ (((r & 8) << 1) | ((r & 4) << 3)));
  }

  f32x4 acc[8][4] = {};
  bf16x8 af[4], bf[4];

#define LDA_SET(mfb, h, bufo) do {                                             \
    af[0] = *(const bf16x8*)(lds + (bufo) + (h) * 16384 + aoff[(mfb) + 0]);    \
    af[1] = *(const bf16x8*)(lds + (bufo) + (h) * 16384 + aoff[(mfb) + 1]);    \
    af[2] = *(const bf16x8*)(lds + (bufo) + (h) * 16384 + aoff[(mfb) + 2]);    \
    af[3] = *(const bf16x8*)(lds + (bufo) + (h) * 16384 + aoff[(mfb) + 3]); } while (0)
#define LDB_SET(h, bufo) do {                                                  \
    bf[0] = *(const bf16x8*)(lds + (bufo) + (h) * 16384 + boff[0]);            \
    bf[1] = *(const bf16x8*)(lds + (bufo) + (h) * 16384 + boff[1]);            \
    bf[2] = *(const bf16x8*)(lds + (bufo) + (h) * 16384 + boff[2]);            \
    bf[3] = *(const bf16x8*)(lds + (bufo) + (h) * 16384 + boff[3]); } while (0)
#define MFMA16(mfb) do {                                                       \
    _Pragma("unroll") for (int i_ = 0; i_ < 4; ++i_)                           \
      { _Pragma("unroll") for (int j_ = 0; j_ < 4; ++j_)                       \
        acc[(mfb) + i_][j_] = __builtin_amdgcn_mfma_f32_16x16x32_bf16(         \
            af[i_], bf[j_], acc[(mfb) + i_][j_], 0, 0, 0); } } while (0)
#define BAR1() do { __builtin_amdgcn_s_barrier(); asm volatile("" ::: "memory"); \
    __builtin_amdgcn_s_setprio(1); } while (0)
#define BAR2() do { __builtin_amdgcn_s_setprio(0);                             \
    asm volatile("" ::: "memory"); __builtin_amdgcn_s_barrier(); } while (0)

  const int NT = K >> 6;                       // 16
  // prologue: tile0 all units, tile1 U0+U1; vmcnt(4) leaves tile1's 2 units in flight
  STG_A(0, 0, 0); STG_B(0, 0, 0); STG_A(0, 1, 0); STG_B(0, 1, 0);
  STG_A(65536, 0, 64); STG_B(65536, 0, 64);
  asm volatile("s_waitcnt vmcnt(4)" ::: "memory");
  __builtin_amdgcn_s_barrier();
  asm volatile("" ::: "memory");

  for (int T = 0; T < NT; ++T) {
    const int bufo = (T & 1) << 16;
    const int obufo = bufo ^ 65536;
    const int k1 = (T + 1) << 6, k2 = (T + 2) << 6;
    // phase 0: mf0-3 x nf0-3 @ k-half 0
    LDA_SET(0, 0, bufo); LDB_SET(0, bufo);
    if (T + 1 < NT) STG_A(obufo, 1, k1);       // T+1.U2 (slot freed T-1.p3.bar2)
    BAR1(); MFMA16(0); BAR2();
    // phase 1: mf4-7 @ k-half 0 (bf reused)
    LDA_SET(4, 0, bufo);
    if (T + 1 < NT) STG_B(obufo, 1, k1);       // T+1.U3
    BAR1(); MFMA16(4); BAR2();
    // phase 2: mf0-3 x nf0-3 @ k-half 1
    LDA_SET(0, 1, bufo); LDB_SET(1, bufo);
    if (T + 2 < NT) STG_A(bufo, 0, k2);        // T+2.U0 (slot freed this-T.p1.bar2)
    BAR1(); MFMA16(0); BAR2();
    // phase 3: mf4-7 @ k-half 1; tile-boundary counted wait
    LDA_SET(4, 1, bufo);
    if (T + 2 < NT) {
      STG_B(bufo, 0, k2);                      // T+2.U1
      asm volatile("s_waitcnt vmcnt(4)" ::: "memory");   // tile T+1 fully landed
    } else {
      asm volatile("s_waitcnt vmcnt(0)" ::: "memory");   // epilogue drain
    }
    BAR1(); MFMA16(4); BAR2();
  }

  // epilogue: bias; Q cols (<1024) scaled by CEXP; V cols (>=2048) -> vT scatter
#pragma unroll
  for (int nf = 0; nf < 4; ++nf) {
    int col = bN + wc * 64 + nf * 16 + l16;
    float bv = bias[col];
#pragma unroll
    for (int mf = 0; mf < 8; ++mf) {
      int row0 = bM + wr * 128 + mf * 16 + quad * 4;
      if (col >= 2048) {
        int hh = (col - 2048) >> 6, dd = (col - 2048) & 63;
        bf16_t o4[4];
        for (int r = 0; r < 4; ++r) o4[r] = (bf16_t)(acc[mf][nf][r] + bv);
        size_t dst = ((((size_t)(row0 >> 11) * NH + hh) * HD + dd) << 11) | (row0 & 2047);
        *(uint2*)&vT[dst] = *(uint2*)o4;
      } else {
        float scale = (col < 1024) ? CEXP : 1.0f;
        for (int r = 0; r < 4; ++r)
          Cout[(size_t)(row0 + r) * N + col] = (bf16_t)((acc[mf][nf][r] + bv) * scale);
      }
    }
  }
#undef STG_A
#undef STG_B
#undef LDA_SET
#undef LDB_SET
#undef MFMA16
#undef BAR1
#undef BAR2
}

// ------------------------------------------------------------- flash attention v9
// Grid (bh=64, SEQ/256=8) = 512 blocks x 512 thr = 2 blocks/CU (LDS 64 KB dbuf)
// = 16 waves/CU = 4 waves/SIMD. Wave owns 32 q (2 subtiles). kb-outer; S^T via
// 16x16x32 (Q pre-scaled by CEXP in gemm1); exp2 direct; PV via 16x16x16 from
// regs. K/V double-buffered, ONE barrier per tile.
// R12: scalar lpart accumulators are load-bearing (f32x4 variant lost 13%).
__global__ __launch_bounds__(512) void attention_v9(
    const bf16_t* __restrict__ qkv, const bf16_t* __restrict__ vT,
    bf16_t* __restrict__ attn) {
  const int t = threadIdx.x;
  const int wave = t >> 6, lane = t & 63;           // wave 0..7
  const int quad = lane >> 4, l16 = lane & 15;
  const int bh = blockIdx.x, b = bh >> 4, h = bh & 15;
  const int qw = blockIdx.y * 256 + wave * 32;

  __shared__ bf16_t Kt[2][128 * 64];   // [key][d], 16B-chunk XOR swizzle by key&7
  __shared__ bf16_t Vt[2][64 * 128];   // [d][key], 16B-chunk XOR swizzle by d&15

  const bf16_t* qglob = qkv + (size_t)b * SEQ * 3072 + h * 64;
  const bf16_t* kglob = qglob + 1024;
  const bf16_t* vglob = vT + (size_t)bh * HD * SEQ;

  bf16x8 qf[2][2];
  for (int s = 0; s < 2; ++s) {
    const bf16_t* qrow = qglob + (size_t)(qw + s * 16 + l16) * 3072 + quad * 8;
    qf[s][0] = *(const bf16x8*)qrow;
    qf[s][1] = *(const bf16x8*)(qrow + 32);
  }

  f32x4 accO[2][4] = {};
  float lpart[2] = {0.f, 0.f};

  const int kRow = lane >> 3, kSlot = lane & 7;
  const int vRow = lane >> 4, vSlot = lane & 15;

  auto stageKV = [&](int buf, int kt) {
    for (int j = 0; j < 2; ++j) {   // K: wave stages keys [wave*16, +16)
      int keyl = wave * 16 + j * 8 + kRow;
      int gc = kSlot ^ (keyl & 7);
      async_ld16((char*)Kt[buf] + (wave * 16 + j * 8) * 128,
                 kglob + (size_t)(kt + keyl) * 3072 + gc * 8);
    }
    for (int j = 0; j < 2; ++j) {   // V: wave stages d [wave*8, +8)
      int d = wave * 8 + j * 4 + vRow;
      int gc = vSlot ^ (d & 15);
      async_ld16((char*)Vt[buf] + (wave * 8 + j * 4) * 256,
                 vglob + (size_t)d * SEQ + kt + gc * 8);
    }
  };

  stageKV(0, 0);

  for (int ti = 0; ti < SEQ / 128; ++ti) {
    const int buf = ti & 1;
    __syncthreads();                       // drain this tile's DMA + publish
    if (ti + 1 < SEQ / 128) stageKV(buf ^ 1, (ti + 1) * 128);

    const bf16_t* KtB = Kt[buf];
    const bf16_t* VtB = Vt[buf];

    for (int kb = 0; kb < 8; ++kb) {
      const bf16_t* kr = &KtB[(kb * 16 + l16) * 64];
      bf16x8 kf0 = *(const bf16x8*)(kr + ((quad ^ (l16 & 7)) * 8));
      bf16x8 kf1 = *(const bf16x8*)(kr + (((4 + quad) ^ (l16 & 7)) * 8));

      short4v pB[2];
      for (int s = 0; s < 2; ++s) {
        f32x4 z = {0.f, 0.f, 0.f, 0.f};
        f32x4 st = __builtin_amdgcn_mfma_f32_16x16x32_bf16(kf0, qf[s][0], z, 0, 0, 0);
        st = __builtin_amdgcn_mfma_f32_16x16x32_bf16(kf1, qf[s][1], st, 0, 0, 0);
        union { bf16_t hh[4]; short4v s4; } u;
        for (int r = 0; r < 4; ++r) {
          float p = __builtin_amdgcn_exp2f(st[r]);   // Q pre-scaled by CEXP
          lpart[s] += p;
          u.hh[r] = (bf16_t)p;
        }
        pB[s] = u.s4;
      }

      const int chunkbase = kb * 2 + (quad >> 1);
      const int coff = (quad & 1) * 4;
      for (int db = 0; db < 4; ++db) {
        short4v vf = *(const short4v*)&VtB[(db * 16 + l16) * 128 +
                                           ((chunkbase ^ l16) * 8) + coff];
        for (int s = 0; s < 2; ++s)
          accO[s][db] = MFMA_PV(vf, pB[s], accO[s][db]);
      }
    }
  }

  for (int s = 0; s < 2; ++s) {
    float l = lpart[s];
    l += __shfl_xor(l, 16);
    l += __shfl_xor(l, 32);
    float inv = 1.f / l;
    size_t tok = (size_t)b * SEQ + qw + s * 16 + l16;
    for (int db = 0; db < 4; ++db) {
      bf16_t o4[4];
      for (int r = 0; r < 4; ++r) o4[r] = (bf16_t)(accO[s][db][r] * inv);
      *(uint2*)&attn[tok * DMODEL + h * HD + db * 16 + quad * 4] = *(uint2*)o4;
    }
  }
}

// ------------------------------------------------------------- launch
extern "C" void kernel_launch(void* const* d_in, const int* in_sizes, int n_in,
                              void* d_out, int out_size, void* d_ws, size_t ws_size,
                              hipStream_t stream) {
  const void* x     = d_in[0];
  const void* w_qkv = d_in[1];
  const void* b_qkv = d_in[2];
  const void* w_out = d_in[3];
  const void* b_out = d_in[4];

  char* ws = (char*)d_ws;
  int*    flag  = (int*)ws;                                    // @0
  bf16_t* wqkvT = (bf16_t*)(ws + 4096);                        // 6.0 MB
  bf16_t* woutT = (bf16_t*)(ws + 6295552);                     // 2.0 MB
  float*  bqkvf = (float*)(ws + 8392704);
  float*  boutf = (float*)(ws + 8404992);
  bf16_t* qkv   = (bf16_t*)(ws + 8409088);                     // 8192x3072 bf16 (50.3 MB)
  bf16_t* xb    = (bf16_t*)(ws + 58740736);                    // 16.8 MB
  bf16_t* attn  = xb;                                          // alias (xb dead after gemm1)
  bf16_t* vTbuf = (bf16_t*)(ws + 75517952);                    // 16.8 MB -> end ~92.3 MB

  sniff_dtype<<<1, 256, 0, stream>>>((const uint4*)x, flag);

  conv_to_bf16<<<NOUT / 2048, 256, 0, stream>>>(x, xb, NOUT, flag);
  conv_biases<<<16, 256, 0, stream>>>(b_qkv, b_out, bqkvf, boutf, flag);

  transpose_w<<<dim3(96, 32), 256, 0, stream>>>(w_qkv, wqkvT, 1024, 3072, flag);
  transpose_w<<<dim3(32, 32), 256, 0, stream>>>(w_out, woutT, 1024, 1024, flag);

  gemm256_qkv<<<dim3(12, 32), 512, 0, stream>>>(
      xb, wqkvT, bqkvf, qkv, NTOK, 3072, 1024, vTbuf);

  attention_v9<<<dim3(BATCH * NH, SEQ / 256), 512, 0, stream>>>(qkv, vTbuf, attn);

  gemm_bt_bias<1><<<dim3(8, 64), 256, 0, stream>>>(
      attn, woutT, boutf, d_out, NTOK, 1024, 1024, flag);
}